// Round 2
// baseline (993.827 us; speedup 1.0000x reference)
//
#include <hip/hip_runtime.h>

#define V_TOT 271633
#define NRR 116
#define CIN 1536   // C*D*D*D = 192*8
#define T_LEN 24
#define B_SZ 8
#define NP (NRR*NRR) // 13456
#define CATN 308     // 116 + 192
#define SPLITS 24

// ---------- counting sort of voxels by ROI label ----------
__global__ void zero_counts_kernel(int* counts) {
    if (threadIdx.x < 128) counts[threadIdx.x] = 0;
}

__global__ void count_kernel(const int* __restrict__ labels, int* __restrict__ counts) {
    int v = blockIdx.x * 256 + threadIdx.x;
    if (v < V_TOT) atomicAdd(&counts[labels[v]], 1);
}

__global__ void prefix_kernel(const int* __restrict__ counts, int* __restrict__ offsets,
                              int* __restrict__ cursor) {
    if (threadIdx.x == 0) {
        int acc = 0;
        for (int r = 0; r < NRR; ++r) { offsets[r] = acc; cursor[r] = acc; acc += counts[r]; }
        offsets[NRR] = acc;
    }
}

__global__ void scatter_kernel(const int* __restrict__ labels, int* __restrict__ cursor,
                               int* __restrict__ perm) {
    int v = blockIdx.x * 256 + threadIdx.x;
    if (v < V_TOT) {
        int pos = atomicAdd(&cursor[labels[v]], 1);
        perm[pos] = v;
    }
}

__device__ __forceinline__ void add4(float4& a, const float4 b) {
    a.x += b.x; a.y += b.y; a.z += b.z; a.w += b.w;
}

// ---------- partial row-sums of fc_w per (ROI, split) ----------
// grid (116, 24), block 384: each thread owns 4 consecutive cols (float4),
// block reads FULL 6KB rows contiguously; 8 rows in flight per thread.
__global__ __launch_bounds__(384) void roi_partial_kernel(
        const float* __restrict__ fc_w, const int* __restrict__ perm,
        const int* __restrict__ counts, const int* __restrict__ offsets,
        float* __restrict__ Wpart) {
    const int r = blockIdx.x, s = blockIdx.y;
    const int n = counts[r], off = offsets[r];
    const int chunk = (n + SPLITS - 1) / SPLITS;
    const int k0 = s * chunk;
    const int k1 = min(k0 + chunk, n);
    const int c4 = threadIdx.x * 4;

    float4 a0{0,0,0,0}, a1{0,0,0,0}, a2{0,0,0,0}, a3{0,0,0,0};
    float4 a4{0,0,0,0}, a5{0,0,0,0}, a6{0,0,0,0}, a7{0,0,0,0};
    int k = k0;
    for (; k + 8 <= k1; k += 8) {
        const int v0 = perm[off+k+0], v1 = perm[off+k+1], v2 = perm[off+k+2], v3 = perm[off+k+3];
        const int v4 = perm[off+k+4], v5 = perm[off+k+5], v6 = perm[off+k+6], v7 = perm[off+k+7];
        const float4 x0 = *(const float4*)(fc_w + (size_t)v0*CIN + c4);
        const float4 x1 = *(const float4*)(fc_w + (size_t)v1*CIN + c4);
        const float4 x2 = *(const float4*)(fc_w + (size_t)v2*CIN + c4);
        const float4 x3 = *(const float4*)(fc_w + (size_t)v3*CIN + c4);
        const float4 x4 = *(const float4*)(fc_w + (size_t)v4*CIN + c4);
        const float4 x5 = *(const float4*)(fc_w + (size_t)v5*CIN + c4);
        const float4 x6 = *(const float4*)(fc_w + (size_t)v6*CIN + c4);
        const float4 x7 = *(const float4*)(fc_w + (size_t)v7*CIN + c4);
        add4(a0, x0); add4(a1, x1); add4(a2, x2); add4(a3, x3);
        add4(a4, x4); add4(a5, x5); add4(a6, x6); add4(a7, x7);
    }
    for (; k < k1; ++k) {
        const int v = perm[off+k];
        add4(a0, *(const float4*)(fc_w + (size_t)v*CIN + c4));
    }
    add4(a0, a1); add4(a2, a3); add4(a4, a5); add4(a6, a7);
    add4(a0, a2); add4(a4, a6); add4(a0, a4);
    *(float4*)(Wpart + ((size_t)(r*SPLITS + s))*CIN + c4) = a0;
}

// ---------- Wbar[r,col] = (sum_s Wpart[r,s,col]) / counts[r] ----------
// grid (6, 116), block 256
__global__ void roi_combine_kernel(const float* __restrict__ Wpart, const int* __restrict__ counts,
                                   float* __restrict__ Wbar) {
    const int col = blockIdx.x * 256 + threadIdx.x;
    const int r = blockIdx.y;
    const float* p = Wpart + (size_t)r * SPLITS * CIN + col;
    float s = 0.f;
    #pragma unroll
    for (int i = 0; i < SPLITS; ++i) s += p[(size_t)i * CIN];
    Wbar[r*CIN + col] = s / (float)counts[r];
}

// bbar[r] = mean over ROI r of fc_b[v]. grid 116, block 64.
__global__ void roi_reduce_b_kernel(const float* __restrict__ fc_b, const int* __restrict__ perm,
                                    const int* __restrict__ counts, const int* __restrict__ offsets,
                                    float* __restrict__ bbar) {
    int r = blockIdx.x;
    int n = counts[r], off = offsets[r];
    float a = 0.f;
    for (int k = threadIdx.x; k < n; k += 64) a += fc_b[perm[off+k]];
    for (int s = 32; s > 0; s >>= 1) a += __shfl_down(a, s);
    if (threadIdx.x == 0) bbar[r] = a / (float)n;
}

// ---------- xbar[b,i] = mean_t x[b,i,t] ----------
__global__ void xbar_kernel(const float* __restrict__ x, float* __restrict__ xbar) {
    int idx = blockIdx.x * 256 + threadIdx.x;
    if (idx < B_SZ * CIN) {
        const float* p = x + (size_t)idx * T_LEN;
        float s = 0.f;
        #pragma unroll
        for (int t = 0; t < T_LEN; ++t) s += p[t];
        xbar[idx] = s * (1.0f / T_LEN);
    }
}

// ---------- x_node[b,r] = xbar[b,:] . Wbar[r,:] + bbar[r] ----------
__global__ void x_node_kernel(const float* __restrict__ xbar, const float* __restrict__ Wbar,
                              const float* __restrict__ bbar, float* __restrict__ x_node) {
    int r = blockIdx.x;
    int lane = threadIdx.x & 63, w = threadIdx.x >> 6;
    const float* wr = Wbar + r * CIN;
    for (int b = w; b < B_SZ; b += 4) {
        const float* xb = xbar + b * CIN;
        float s = 0.f;
        for (int i = lane; i < CIN; i += 64) s += xb[i] * wr[i];
        for (int sft = 32; sft > 0; sft >>= 1) s += __shfl_down(s, sft);
        if (lane == 0) x_node[b * NRR + r] = s + bbar[r];
    }
}

// ---------- per-ROI tiny MLPs: one wave per (b, r) ----------
__global__ void fs_mlp_kernel(const float* __restrict__ x_node,
                              const float* __restrict__ w1, const float* __restrict__ b1,
                              const float* __restrict__ w2, const float* __restrict__ b2,
                              const float* __restrict__ w3, const float* __restrict__ b3,
                              float* __restrict__ fx) {
    int w = blockIdx.x * 4 + (threadIdx.x >> 6);
    int lane = threadIdx.x & 63;
    int b = w / NRR, r = w % NRR;
    float xn = x_node[b * NRR + r];
    float h1 = fmaxf(xn * w1[r*64 + lane] + b1[r*64 + lane], 0.f);
    const float* w2row = w2 + ((size_t)r*64 + lane) * 64;
    float acc = b2[r*64 + lane];
    #pragma unroll
    for (int i = 0; i < 64; ++i) acc += __shfl(h1, i) * w2row[i];
    float h2 = fmaxf(acc, 0.f);
    float p = h2 * w3[r*64 + lane];
    for (int s = 32; s > 0; s >>= 1) p += __shfl_down(p, s);
    if (lane == 0) fx[b * NRR + r] = p + b3[r];
}

// ---------- distance MLP: one wave per pair p ----------
__global__ void dist_mlp_kernel(const float* __restrict__ dist,
                                const float* __restrict__ mw1, const float* __restrict__ mb1,
                                const float* __restrict__ mw2, const float* __restrict__ mb2,
                                const float* __restrict__ mw3, const float* __restrict__ mb3,
                                float* __restrict__ md) {
    int p = blockIdx.x * 4 + (threadIdx.x >> 6);
    int lane = threadIdx.x & 63;
    float d = dist[p];
    float g1 = fmaxf(d * mw1[lane] + mb1[lane], 0.f);
    const float* w2row = mw2 + lane * 64;
    float acc = mb2[lane];
    #pragma unroll
    for (int i = 0; i < 64; ++i) acc += __shfl(g1, i) * w2row[i];
    float g2 = fmaxf(acc, 0.f);
    float t = g2 * mw3[lane];
    for (int s = 32; s > 0; s >>= 1) t += __shfl_down(t, s);
    if (lane == 0) md[p] = t + mb3[0];
}

// ---------- mmat[j] = fc1_w[j,:] . md + fc1_b[j], j<64 ----------
__global__ void fc1_kernel(const float* __restrict__ fc1_w, const float* __restrict__ fc1_b,
                           const float* __restrict__ md, float* __restrict__ mmat) {
    int j = blockIdx.x;
    const float* row = fc1_w + (size_t)j * NP;
    float s = 0.f;
    for (int p = threadIdx.x; p < NP; p += 256) s += row[p] * md[p];
    __shared__ float red[4];
    for (int sft = 32; sft > 0; sft >>= 1) s += __shfl_down(s, sft);
    if ((threadIdx.x & 63) == 0) red[threadIdx.x >> 6] = s;
    __syncthreads();
    if (threadIdx.x == 0) mmat[j] = red[0] + red[1] + red[2] + red[3] + fc1_b[j];
}

// ---------- mf + pooled -> cat[8][308] ----------
__global__ void tail_a_kernel(const float* __restrict__ mmat, const float* __restrict__ fx,
                              const float* __restrict__ xbar, float* __restrict__ cat) {
    for (int idx = threadIdx.x; idx < B_SZ * NRR; idx += 256) {
        int b = idx / NRR, r = idx % NRR;
        float s = 0.f;
        #pragma unroll
        for (int k = 0; k < 8; ++k) s += mmat[b*8 + k] * fx[k * NRR + r];
        cat[b * CATN + r] = s;
    }
    for (int idx = threadIdx.x; idx < B_SZ * 192; idx += 256) {
        int b = idx / 192, c = idx % 192;
        float s = 0.f;
        #pragma unroll
        for (int j = 0; j < 8; ++j) s += xbar[b * CIN + c*8 + j];
        cat[b * CATN + NRR + c] = s * (1.0f / 8.0f);
    }
}

// ---------- weff[k] = sum_j hidden_w[j,k]*out_w[j]; weff[308] = beff ----------
__global__ void weff_kernel(const float* __restrict__ hidden_w, const float* __restrict__ hidden_b,
                            const float* __restrict__ out_w, const float* __restrict__ out_b,
                            float* __restrict__ weff) {
    int k = blockIdx.x * 256 + threadIdx.x;
    if (k < CATN) {
        float s = 0.f;
        for (int j = 0; j < 768; ++j) s += hidden_w[(size_t)j * CATN + k] * out_w[j];
        weff[k] = s;
    } else if (k == CATN) {
        float s = 0.f;
        for (int j = 0; j < 768; ++j) s += hidden_b[j] * out_w[j];
        weff[CATN] = s + out_b[0];
    }
}

// ---------- out[b] = cat[b,:] . weff + beff ----------
__global__ void out_kernel(const float* __restrict__ cat, const float* __restrict__ weff,
                           float* __restrict__ out) {
    int b = threadIdx.x >> 6, lane = threadIdx.x & 63;
    float s = 0.f;
    for (int k = lane; k < CATN; k += 64) s += cat[b * CATN + k] * weff[k];
    for (int sft = 32; sft > 0; sft >>= 1) s += __shfl_down(s, sft);
    if (lane == 0) out[b] = s + weff[CATN];
}

extern "C" void kernel_launch(void* const* d_in, const int* in_sizes, int n_in,
                              void* d_out, int out_size, void* d_ws, size_t ws_size,
                              hipStream_t stream) {
    const float* x        = (const float*)d_in[0];
    const int*   labels   = (const int*)d_in[1];
    const float* dist     = (const float*)d_in[2];
    const float* fc_w     = (const float*)d_in[3];
    const float* fc_b     = (const float*)d_in[4];
    const float* fs_w1    = (const float*)d_in[5];
    const float* fs_b1    = (const float*)d_in[6];
    const float* fs_w2    = (const float*)d_in[7];
    const float* fs_b2    = (const float*)d_in[8];
    const float* fs_w3    = (const float*)d_in[9];
    const float* fs_b3    = (const float*)d_in[10];
    const float* m_w1     = (const float*)d_in[11];
    const float* m_b1     = (const float*)d_in[12];
    const float* m_w2     = (const float*)d_in[13];
    const float* m_b2     = (const float*)d_in[14];
    const float* m_w3     = (const float*)d_in[15];
    const float* m_b3     = (const float*)d_in[16];
    const float* fc1_w    = (const float*)d_in[17];
    const float* fc1_b    = (const float*)d_in[18];
    const float* hidden_w = (const float*)d_in[19];
    const float* hidden_b = (const float*)d_in[20];
    const float* out_w    = (const float*)d_in[21];
    const float* out_b    = (const float*)d_in[22];
    float* out = (float*)d_out;

    // workspace layout
    int* counts  = (int*)d_ws;           // 128
    int* offsets = counts + 128;         // 128
    int* cursor  = offsets + 128;        // 128
    int* perm    = cursor + 128;         // V_TOT
    float* fb = (float*)(perm + ((V_TOT + 255) / 256) * 256);
    float* Wpart  = fb;  fb += (size_t)NRR * SPLITS * CIN;  // ~17 MB
    float* Wbar   = fb;  fb += NRR * CIN;
    float* bbar   = fb;  fb += 128;
    float* xbar   = fb;  fb += B_SZ * CIN;
    float* x_node = fb;  fb += B_SZ * NRR;
    float* fx     = fb;  fb += B_SZ * NRR;
    float* md     = fb;  fb += NP;
    float* mmat   = fb;  fb += 64;
    float* cat    = fb;  fb += B_SZ * CATN;
    float* weff   = fb;  fb += 320;

    const int vblocks = (V_TOT + 255) / 256;

    zero_counts_kernel<<<1, 128, 0, stream>>>(counts);
    count_kernel<<<vblocks, 256, 0, stream>>>(labels, counts);
    prefix_kernel<<<1, 64, 0, stream>>>(counts, offsets, cursor);
    scatter_kernel<<<vblocks, 256, 0, stream>>>(labels, cursor, perm);
    roi_partial_kernel<<<dim3(NRR, SPLITS), 384, 0, stream>>>(fc_w, perm, counts, offsets, Wpart);
    roi_combine_kernel<<<dim3(6, NRR), 256, 0, stream>>>(Wpart, counts, Wbar);
    roi_reduce_b_kernel<<<NRR, 64, 0, stream>>>(fc_b, perm, counts, offsets, bbar);
    xbar_kernel<<<(B_SZ * CIN + 255) / 256, 256, 0, stream>>>(x, xbar);
    x_node_kernel<<<NRR, 256, 0, stream>>>(xbar, Wbar, bbar, x_node);
    fs_mlp_kernel<<<232, 256, 0, stream>>>(x_node, fs_w1, fs_b1, fs_w2, fs_b2, fs_w3, fs_b3, fx);
    dist_mlp_kernel<<<NP / 4, 256, 0, stream>>>(dist, m_w1, m_b1, m_w2, m_b2, m_w3, m_b3, md);
    fc1_kernel<<<64, 256, 0, stream>>>(fc1_w, fc1_b, md, mmat);
    tail_a_kernel<<<1, 256, 0, stream>>>(mmat, fx, xbar, cat);
    weff_kernel<<<2, 256, 0, stream>>>(hidden_w, hidden_b, out_w, out_b, weff);
    out_kernel<<<1, 512, 0, stream>>>(cat, weff, out);
}

// Round 3
// 522.574 us; speedup vs baseline: 1.9018x; 1.9018x over previous
//
#include <hip/hip_runtime.h>

#define V_TOT 271633
#define NRR 116
#define CIN 1536   // C*D*D*D = 192*8
#define T_LEN 24
#define B_SZ 8
#define NP (NRR*NRR) // 13456
#define CATN 308     // 116 + 192
#define SPLITS 24
#define VB 1062      // ceil(V_TOT/256)

// ---------- deterministic counting sort: hist -> scan -> scatter ----------
__global__ __launch_bounds__(256) void hist_kernel(const int* __restrict__ labels,
                                                   int* __restrict__ blockHist) {
    __shared__ int h[NRR];
    for (int i = threadIdx.x; i < NRR; i += 256) h[i] = 0;
    __syncthreads();
    int v = blockIdx.x * 256 + threadIdx.x;
    if (v < V_TOT) atomicAdd(&h[labels[v]], 1);
    __syncthreads();
    for (int i = threadIdx.x; i < NRR; i += 256)
        blockHist[(size_t)i * VB + blockIdx.x] = h[i];
}

// one block per bin: exclusive scan of blockHist[r][0..VB) -> blockBase, total -> counts[r]
__global__ __launch_bounds__(256) void binscan_kernel(const int* __restrict__ blockHist,
                                                      int* __restrict__ blockBase,
                                                      int* __restrict__ counts) {
    const int r = blockIdx.x;
    const int lane = threadIdx.x & 63, w = threadIdx.x >> 6;
    __shared__ int wsum[4];
    int run = 0;
    for (int base = 0; base < VB; base += 256) {
        const int i = base + threadIdx.x;
        const int orig = (i < VB) ? blockHist[(size_t)r * VB + i] : 0;
        int val = orig;
        #pragma unroll
        for (int off = 1; off < 64; off <<= 1) {
            int t = __shfl_up(val, off);
            if (lane >= off) val += t;
        }
        if (lane == 63) wsum[w] = val;
        __syncthreads();
        int woff = 0;
        #pragma unroll
        for (int j = 0; j < 4; ++j) if (j < w) woff += wsum[j];
        if (i < VB) blockBase[(size_t)r * VB + i] = run + woff + val - orig;
        int tot = wsum[0] + wsum[1] + wsum[2] + wsum[3];
        __syncthreads();
        run += tot;
    }
    if (threadIdx.x == 0) counts[r] = run;
}

__global__ void offsets_kernel(const int* __restrict__ counts, int* __restrict__ offsets) {
    if (threadIdx.x == 0) {
        int acc = 0;
        for (int r = 0; r < NRR; ++r) { offsets[r] = acc; acc += counts[r]; }
        offsets[NRR] = acc;
    }
}

__global__ __launch_bounds__(256) void scatter_kernel(const int* __restrict__ labels,
                                                      const int* __restrict__ offsets,
                                                      const int* __restrict__ blockBase,
                                                      int* __restrict__ perm) {
    __shared__ int lab[256];
    const int v = blockIdx.x * 256 + threadIdx.x;
    const int r = (v < V_TOT) ? labels[v] : -1;
    lab[threadIdx.x] = r;
    __syncthreads();
    if (r >= 0) {
        int rank = 0;
        for (int t = 0; t < (int)threadIdx.x; ++t) rank += (lab[t] == r);
        perm[offsets[r] + blockBase[(size_t)r * VB + blockIdx.x] + rank] = v;
    }
}

__device__ __forceinline__ void add4(float4& a, const float4 b) {
    a.x += b.x; a.y += b.y; a.z += b.z; a.w += b.w;
}

// ---------- partial row-sums of fc_w per (ROI, split) ----------
// grid (116, 24), block 384: full 6KB rows contiguous; 8 rows in flight/thread.
__global__ __launch_bounds__(384) void roi_partial_kernel(
        const float* __restrict__ fc_w, const int* __restrict__ perm,
        const int* __restrict__ counts, const int* __restrict__ offsets,
        float* __restrict__ Wpart) {
    const int r = blockIdx.x, s = blockIdx.y;
    const int n = counts[r], off = offsets[r];
    const int chunk = (n + SPLITS - 1) / SPLITS;
    const int k0 = s * chunk;
    const int k1 = min(k0 + chunk, n);
    const int c4 = threadIdx.x * 4;

    float4 a0{0,0,0,0}, a1{0,0,0,0}, a2{0,0,0,0}, a3{0,0,0,0};
    float4 a4{0,0,0,0}, a5{0,0,0,0}, a6{0,0,0,0}, a7{0,0,0,0};
    int k = k0;
    for (; k + 8 <= k1; k += 8) {
        const int v0 = perm[off+k+0], v1 = perm[off+k+1], v2 = perm[off+k+2], v3 = perm[off+k+3];
        const int v4 = perm[off+k+4], v5 = perm[off+k+5], v6 = perm[off+k+6], v7 = perm[off+k+7];
        const float4 x0 = *(const float4*)(fc_w + (size_t)v0*CIN + c4);
        const float4 x1 = *(const float4*)(fc_w + (size_t)v1*CIN + c4);
        const float4 x2 = *(const float4*)(fc_w + (size_t)v2*CIN + c4);
        const float4 x3 = *(const float4*)(fc_w + (size_t)v3*CIN + c4);
        const float4 x4 = *(const float4*)(fc_w + (size_t)v4*CIN + c4);
        const float4 x5 = *(const float4*)(fc_w + (size_t)v5*CIN + c4);
        const float4 x6 = *(const float4*)(fc_w + (size_t)v6*CIN + c4);
        const float4 x7 = *(const float4*)(fc_w + (size_t)v7*CIN + c4);
        add4(a0, x0); add4(a1, x1); add4(a2, x2); add4(a3, x3);
        add4(a4, x4); add4(a5, x5); add4(a6, x6); add4(a7, x7);
    }
    for (; k < k1; ++k) {
        const int v = perm[off+k];
        add4(a0, *(const float4*)(fc_w + (size_t)v*CIN + c4));
    }
    add4(a0, a1); add4(a2, a3); add4(a4, a5); add4(a6, a7);
    add4(a0, a2); add4(a4, a6); add4(a0, a4);
    *(float4*)(Wpart + ((size_t)(r*SPLITS + s))*CIN + c4) = a0;
}

// bbar[r] = mean over ROI r of fc_b[v]. grid 116, block 64.
__global__ void roi_reduce_b_kernel(const float* __restrict__ fc_b, const int* __restrict__ perm,
                                    const int* __restrict__ counts, const int* __restrict__ offsets,
                                    float* __restrict__ bbar) {
    int r = blockIdx.x;
    int n = counts[r], off = offsets[r];
    float a = 0.f;
    for (int k = threadIdx.x; k < n; k += 64) a += fc_b[perm[off+k]];
    for (int s = 32; s > 0; s >>= 1) a += __shfl_down(a, s);
    if (threadIdx.x == 0) bbar[r] = a / (float)n;
}

// ---------- xbar[b,i] = mean_t x[b,i,t] ----------
__global__ void xbar_kernel(const float* __restrict__ x, float* __restrict__ xbar) {
    int idx = blockIdx.x * 256 + threadIdx.x;
    if (idx < B_SZ * CIN) {
        const float* p = x + (size_t)idx * T_LEN;
        float s = 0.f;
        #pragma unroll
        for (int t = 0; t < T_LEN; ++t) s += p[t];
        xbar[idx] = s * (1.0f / T_LEN);
    }
}

// ---------- x_node[b,r] = (sum_s Wpart[r,s,:]).xbar[b,:]/counts[r] + bbar[r] ----------
// grid 116, block 256
__global__ __launch_bounds__(256) void x_node_kernel(const float* __restrict__ Wpart,
                                                     const int* __restrict__ counts,
                                                     const float* __restrict__ bbar,
                                                     const float* __restrict__ xbar,
                                                     float* __restrict__ x_node) {
    const int r = blockIdx.x;
    float acc[B_SZ] = {0,0,0,0,0,0,0,0};
    for (int c = threadIdx.x; c < CIN; c += 256) {
        float wsum = 0.f;
        #pragma unroll
        for (int s = 0; s < SPLITS; ++s) wsum += Wpart[((size_t)(r*SPLITS + s))*CIN + c];
        #pragma unroll
        for (int b = 0; b < B_SZ; ++b) acc[b] += wsum * xbar[b*CIN + c];
    }
    __shared__ float red[B_SZ][4];
    const int lane = threadIdx.x & 63, w = threadIdx.x >> 6;
    #pragma unroll
    for (int b = 0; b < B_SZ; ++b) {
        float s = acc[b];
        for (int sft = 32; sft > 0; sft >>= 1) s += __shfl_down(s, sft);
        if (lane == 0) red[b][w] = s;
    }
    __syncthreads();
    if (threadIdx.x < B_SZ) {
        float s = red[threadIdx.x][0] + red[threadIdx.x][1] + red[threadIdx.x][2] + red[threadIdx.x][3];
        x_node[threadIdx.x * NRR + r] = s / (float)counts[r] + bbar[r];
    }
}

// ---------- per-ROI tiny MLPs: one wave per (b, r) ----------
__global__ void fs_mlp_kernel(const float* __restrict__ x_node,
                              const float* __restrict__ w1, const float* __restrict__ b1,
                              const float* __restrict__ w2, const float* __restrict__ b2,
                              const float* __restrict__ w3, const float* __restrict__ b3,
                              float* __restrict__ fx) {
    int w = blockIdx.x * 4 + (threadIdx.x >> 6);
    int lane = threadIdx.x & 63;
    int b = w / NRR, r = w % NRR;
    float xn = x_node[b * NRR + r];
    float h1 = fmaxf(xn * w1[r*64 + lane] + b1[r*64 + lane], 0.f);
    const float* w2row = w2 + ((size_t)r*64 + lane) * 64;
    float acc = b2[r*64 + lane];
    #pragma unroll
    for (int i = 0; i < 64; ++i) acc += __shfl(h1, i) * w2row[i];
    float h2 = fmaxf(acc, 0.f);
    float p = h2 * w3[r*64 + lane];
    for (int s = 32; s > 0; s >>= 1) p += __shfl_down(p, s);
    if (lane == 0) fx[b * NRR + r] = p + b3[r];
}

// ---------- distance MLP: one wave per pair p ----------
__global__ void dist_mlp_kernel(const float* __restrict__ dist,
                                const float* __restrict__ mw1, const float* __restrict__ mb1,
                                const float* __restrict__ mw2, const float* __restrict__ mb2,
                                const float* __restrict__ mw3, const float* __restrict__ mb3,
                                float* __restrict__ md) {
    int p = blockIdx.x * 4 + (threadIdx.x >> 6);
    int lane = threadIdx.x & 63;
    float d = dist[p];
    float g1 = fmaxf(d * mw1[lane] + mb1[lane], 0.f);
    const float* w2row = mw2 + lane * 64;
    float acc = mb2[lane];
    #pragma unroll
    for (int i = 0; i < 64; ++i) acc += __shfl(g1, i) * w2row[i];
    float g2 = fmaxf(acc, 0.f);
    float t = g2 * mw3[lane];
    for (int s = 32; s > 0; s >>= 1) t += __shfl_down(t, s);
    if (lane == 0) md[p] = t + mb3[0];
}

// ---------- mmat[j] = fc1_w[j,:] . md + fc1_b[j], j<64 ----------
__global__ void fc1_kernel(const float* __restrict__ fc1_w, const float* __restrict__ fc1_b,
                           const float* __restrict__ md, float* __restrict__ mmat) {
    int j = blockIdx.x;
    const float* row = fc1_w + (size_t)j * NP;
    float s = 0.f;
    for (int p = threadIdx.x; p < NP; p += 256) s += row[p] * md[p];
    __shared__ float red[4];
    for (int sft = 32; sft > 0; sft >>= 1) s += __shfl_down(s, sft);
    if ((threadIdx.x & 63) == 0) red[threadIdx.x >> 6] = s;
    __syncthreads();
    if (threadIdx.x == 0) mmat[j] = red[0] + red[1] + red[2] + red[3] + fc1_b[j];
}

// ---------- mf + pooled -> cat[8][308] ----------
__global__ void tail_a_kernel(const float* __restrict__ mmat, const float* __restrict__ fx,
                              const float* __restrict__ xbar, float* __restrict__ cat) {
    for (int idx = threadIdx.x; idx < B_SZ * NRR; idx += 256) {
        int b = idx / NRR, r = idx % NRR;
        float s = 0.f;
        #pragma unroll
        for (int k = 0; k < 8; ++k) s += mmat[b*8 + k] * fx[k * NRR + r];
        cat[b * CATN + r] = s;
    }
    for (int idx = threadIdx.x; idx < B_SZ * 192; idx += 256) {
        int b = idx / 192, c = idx % 192;
        float s = 0.f;
        #pragma unroll
        for (int j = 0; j < 8; ++j) s += xbar[b * CIN + c*8 + j];
        cat[b * CATN + NRR + c] = s * (1.0f / 8.0f);
    }
}

// ---------- weff[k] = sum_j hidden_w[j,k]*out_w[j]; weff[308] = beff ----------
__global__ void weff_kernel(const float* __restrict__ hidden_w, const float* __restrict__ hidden_b,
                            const float* __restrict__ out_w, const float* __restrict__ out_b,
                            float* __restrict__ weff) {
    int k = blockIdx.x * 256 + threadIdx.x;
    if (k < CATN) {
        float s = 0.f;
        for (int j = 0; j < 768; ++j) s += hidden_w[(size_t)j * CATN + k] * out_w[j];
        weff[k] = s;
    } else if (k == CATN) {
        float s = 0.f;
        for (int j = 0; j < 768; ++j) s += hidden_b[j] * out_w[j];
        weff[CATN] = s + out_b[0];
    }
}

// ---------- out[b] = cat[b,:] . weff + beff ----------
__global__ void out_kernel(const float* __restrict__ cat, const float* __restrict__ weff,
                           float* __restrict__ out) {
    int b = threadIdx.x >> 6, lane = threadIdx.x & 63;
    float s = 0.f;
    for (int k = lane; k < CATN; k += 64) s += cat[b * CATN + k] * weff[k];
    for (int sft = 32; sft > 0; sft >>= 1) s += __shfl_down(s, sft);
    if (lane == 0) out[b] = s + weff[CATN];
}

extern "C" void kernel_launch(void* const* d_in, const int* in_sizes, int n_in,
                              void* d_out, int out_size, void* d_ws, size_t ws_size,
                              hipStream_t stream) {
    const float* x        = (const float*)d_in[0];
    const int*   labels   = (const int*)d_in[1];
    const float* dist     = (const float*)d_in[2];
    const float* fc_w     = (const float*)d_in[3];
    const float* fc_b     = (const float*)d_in[4];
    const float* fs_w1    = (const float*)d_in[5];
    const float* fs_b1    = (const float*)d_in[6];
    const float* fs_w2    = (const float*)d_in[7];
    const float* fs_b2    = (const float*)d_in[8];
    const float* fs_w3    = (const float*)d_in[9];
    const float* fs_b3    = (const float*)d_in[10];
    const float* m_w1     = (const float*)d_in[11];
    const float* m_b1     = (const float*)d_in[12];
    const float* m_w2     = (const float*)d_in[13];
    const float* m_b2     = (const float*)d_in[14];
    const float* m_w3     = (const float*)d_in[15];
    const float* m_b3     = (const float*)d_in[16];
    const float* fc1_w    = (const float*)d_in[17];
    const float* fc1_b    = (const float*)d_in[18];
    const float* hidden_w = (const float*)d_in[19];
    const float* hidden_b = (const float*)d_in[20];
    const float* out_w    = (const float*)d_in[21];
    const float* out_b    = (const float*)d_in[22];
    float* out = (float*)d_out;

    // workspace layout
    int* counts    = (int*)d_ws;               // 128
    int* offsets   = counts + 128;             // 128
    int* blockHist = offsets + 128;            // NRR*VB
    int* blockBase = blockHist + NRR*VB;       // NRR*VB
    int* perm      = blockBase + NRR*VB;       // V_TOT
    float* fb = (float*)(perm + ((V_TOT + 255) / 256) * 256);
    float* Wpart  = fb;  fb += (size_t)NRR * SPLITS * CIN;  // ~17 MB
    float* bbar   = fb;  fb += 128;
    float* xbar   = fb;  fb += B_SZ * CIN;
    float* x_node = fb;  fb += B_SZ * NRR;
    float* fx     = fb;  fb += B_SZ * NRR;
    float* md     = fb;  fb += NP;
    float* mmat   = fb;  fb += 64;
    float* cat    = fb;  fb += B_SZ * CATN;
    float* weff   = fb;  fb += 320;

    hist_kernel<<<VB, 256, 0, stream>>>(labels, blockHist);
    binscan_kernel<<<NRR, 256, 0, stream>>>(blockHist, blockBase, counts);
    offsets_kernel<<<1, 64, 0, stream>>>(counts, offsets);
    scatter_kernel<<<VB, 256, 0, stream>>>(labels, offsets, blockBase, perm);
    roi_partial_kernel<<<dim3(NRR, SPLITS), 384, 0, stream>>>(fc_w, perm, counts, offsets, Wpart);
    roi_reduce_b_kernel<<<NRR, 64, 0, stream>>>(fc_b, perm, counts, offsets, bbar);
    xbar_kernel<<<(B_SZ * CIN + 255) / 256, 256, 0, stream>>>(x, xbar);
    x_node_kernel<<<NRR, 256, 0, stream>>>(Wpart, counts, bbar, xbar, x_node);
    fs_mlp_kernel<<<232, 256, 0, stream>>>(x_node, fs_w1, fs_b1, fs_w2, fs_b2, fs_w3, fs_b3, fx);
    dist_mlp_kernel<<<NP / 4, 256, 0, stream>>>(dist, m_w1, m_b1, m_w2, m_b2, m_w3, m_b3, md);
    fc1_kernel<<<64, 256, 0, stream>>>(fc1_w, fc1_b, md, mmat);
    tail_a_kernel<<<1, 256, 0, stream>>>(mmat, fx, xbar, cat);
    weff_kernel<<<2, 256, 0, stream>>>(hidden_w, hidden_b, out_w, out_b, weff);
    out_kernel<<<1, 512, 0, stream>>>(cat, weff, out);
}

// Round 4
// 426.675 us; speedup vs baseline: 2.3292x; 1.2248x over previous
//
#include <hip/hip_runtime.h>

#define V_TOT 271633
#define NRR 116
#define CIN 1536   // C*D*D*D = 192*8
#define T_LEN 24
#define B_SZ 8
#define NP (NRR*NRR) // 13456
#define CATN 308     // 116 + 192
#define SPLITS 44
#define VB 1062      // ceil(V_TOT/256)

// ---------- deterministic counting sort: hist -> scan -> scatter ----------
__global__ __launch_bounds__(256) void hist_kernel(const int* __restrict__ labels,
                                                   int* __restrict__ blockHist) {
    __shared__ int h[NRR];
    for (int i = threadIdx.x; i < NRR; i += 256) h[i] = 0;
    __syncthreads();
    int v = blockIdx.x * 256 + threadIdx.x;
    if (v < V_TOT) atomicAdd(&h[labels[v]], 1);
    __syncthreads();
    for (int i = threadIdx.x; i < NRR; i += 256)
        blockHist[(size_t)i * VB + blockIdx.x] = h[i];
}

__global__ __launch_bounds__(256) void binscan_kernel(const int* __restrict__ blockHist,
                                                      int* __restrict__ blockBase,
                                                      int* __restrict__ counts) {
    const int r = blockIdx.x;
    const int lane = threadIdx.x & 63, w = threadIdx.x >> 6;
    __shared__ int wsum[4];
    int run = 0;
    for (int base = 0; base < VB; base += 256) {
        const int i = base + threadIdx.x;
        const int orig = (i < VB) ? blockHist[(size_t)r * VB + i] : 0;
        int val = orig;
        #pragma unroll
        for (int off = 1; off < 64; off <<= 1) {
            int t = __shfl_up(val, off);
            if (lane >= off) val += t;
        }
        if (lane == 63) wsum[w] = val;
        __syncthreads();
        int woff = 0;
        #pragma unroll
        for (int j = 0; j < 4; ++j) if (j < w) woff += wsum[j];
        if (i < VB) blockBase[(size_t)r * VB + i] = run + woff + val - orig;
        int tot = wsum[0] + wsum[1] + wsum[2] + wsum[3];
        __syncthreads();
        run += tot;
    }
    if (threadIdx.x == 0) counts[r] = run;
}

__global__ void offsets_kernel(const int* __restrict__ counts, int* __restrict__ offsets) {
    if (threadIdx.x == 0) {
        int acc = 0;
        for (int r = 0; r < NRR; ++r) { offsets[r] = acc; acc += counts[r]; }
        offsets[NRR] = acc;
    }
}

__global__ __launch_bounds__(256) void scatter_kernel(const int* __restrict__ labels,
                                                      const int* __restrict__ offsets,
                                                      const int* __restrict__ blockBase,
                                                      int* __restrict__ perm) {
    __shared__ int lab[256];
    const int v = blockIdx.x * 256 + threadIdx.x;
    const int r = (v < V_TOT) ? labels[v] : -1;
    lab[threadIdx.x] = r;
    __syncthreads();
    if (r >= 0) {
        int rank = 0;
        for (int t = 0; t < (int)threadIdx.x; ++t) rank += (lab[t] == r);
        perm[offsets[r] + blockBase[(size_t)r * VB + blockIdx.x] + rank] = v;
    }
}

__device__ __forceinline__ void add4(float4& a, const float4 b) {
    a.x += b.x; a.y += b.y; a.z += b.z; a.w += b.w;
}

// ---------- xbar[b,i] = mean_t x[b,i,t] ----------
__global__ void xbar_kernel(const float* __restrict__ x, float* __restrict__ xbar) {
    int idx = blockIdx.x * 256 + threadIdx.x;
    if (idx < B_SZ * CIN) {
        const float* p = x + (size_t)idx * T_LEN;
        float s = 0.f;
        #pragma unroll
        for (int t = 0; t < T_LEN; ++t) s += p[t];
        xbar[idx] = s * (1.0f / T_LEN);
    }
}

// ---------- fused partial row-sum of fc_w + dot with xbar ----------
// grid (116, 44), block 384. Each block: partial row-sum (registers) of its
// voxel chunk, then dots with xbar[8][1536] -> 8 floats to dotpart[r][s][8].
__global__ __launch_bounds__(384) void roi_partial_dot_kernel(
        const float* __restrict__ fc_w, const int* __restrict__ perm,
        const int* __restrict__ counts, const int* __restrict__ offsets,
        const float* __restrict__ xbar, float* __restrict__ dotpart) {
    const int r = blockIdx.x, s = blockIdx.y;
    const int n = counts[r], off = offsets[r];
    const int chunk = (n + SPLITS - 1) / SPLITS;
    const int k0 = min(s * chunk, n);
    const int k1 = min(k0 + chunk, n);
    const int c4 = threadIdx.x * 4;

    float4 a0{0,0,0,0}, a1{0,0,0,0}, a2{0,0,0,0}, a3{0,0,0,0};
    float4 a4{0,0,0,0}, a5{0,0,0,0}, a6{0,0,0,0}, a7{0,0,0,0};
    int k = k0;
    for (; k + 8 <= k1; k += 8) {
        const int v0 = perm[off+k+0], v1 = perm[off+k+1], v2 = perm[off+k+2], v3 = perm[off+k+3];
        const int v4 = perm[off+k+4], v5 = perm[off+k+5], v6 = perm[off+k+6], v7 = perm[off+k+7];
        const float4 x0 = *(const float4*)(fc_w + (size_t)v0*CIN + c4);
        const float4 x1 = *(const float4*)(fc_w + (size_t)v1*CIN + c4);
        const float4 x2 = *(const float4*)(fc_w + (size_t)v2*CIN + c4);
        const float4 x3 = *(const float4*)(fc_w + (size_t)v3*CIN + c4);
        const float4 x4 = *(const float4*)(fc_w + (size_t)v4*CIN + c4);
        const float4 x5 = *(const float4*)(fc_w + (size_t)v5*CIN + c4);
        const float4 x6 = *(const float4*)(fc_w + (size_t)v6*CIN + c4);
        const float4 x7 = *(const float4*)(fc_w + (size_t)v7*CIN + c4);
        add4(a0, x0); add4(a1, x1); add4(a2, x2); add4(a3, x3);
        add4(a4, x4); add4(a5, x5); add4(a6, x6); add4(a7, x7);
    }
    for (; k < k1; ++k) {
        const int v = perm[off+k];
        add4(a0, *(const float4*)(fc_w + (size_t)v*CIN + c4));
    }
    add4(a0, a1); add4(a2, a3); add4(a4, a5); add4(a6, a7);
    add4(a0, a2); add4(a4, a6); add4(a0, a4);

    // dot partial row-sum (a0 = cols c4..c4+3) with xbar[b]
    float d[B_SZ];
    #pragma unroll
    for (int b = 0; b < B_SZ; ++b) {
        const float4 xb = *(const float4*)(xbar + b*CIN + c4);
        d[b] = a0.x*xb.x + a0.y*xb.y + a0.z*xb.z + a0.w*xb.w;
    }
    __shared__ float red[6*B_SZ];
    const int lane = threadIdx.x & 63, w = threadIdx.x >> 6;
    #pragma unroll
    for (int b = 0; b < B_SZ; ++b) {
        float v = d[b];
        for (int sft = 32; sft > 0; sft >>= 1) v += __shfl_down(v, sft);
        if (lane == 0) red[w*B_SZ + b] = v;
    }
    __syncthreads();
    if (threadIdx.x < B_SZ) {
        float v = 0.f;
        #pragma unroll
        for (int j = 0; j < 6; ++j) v += red[j*B_SZ + threadIdx.x];
        dotpart[((size_t)(r*SPLITS + s))*B_SZ + threadIdx.x] = v;
    }
}

// bbar[r] = mean over ROI r of fc_b[v]. grid 116, block 64.
__global__ void roi_reduce_b_kernel(const float* __restrict__ fc_b, const int* __restrict__ perm,
                                    const int* __restrict__ counts, const int* __restrict__ offsets,
                                    float* __restrict__ bbar) {
    int r = blockIdx.x;
    int n = counts[r], off = offsets[r];
    float a = 0.f;
    for (int k = threadIdx.x; k < n; k += 64) a += fc_b[perm[off+k]];
    for (int s = 32; s > 0; s >>= 1) a += __shfl_down(a, s);
    if (threadIdx.x == 0) bbar[r] = a / (float)n;
}

// ---------- fused x_node finalize + per-ROI tiny MLPs: one wave per (b,r) ----------
__global__ void fs_mlp_kernel(const float* __restrict__ dotpart, const int* __restrict__ counts,
                              const float* __restrict__ bbar,
                              const float* __restrict__ w1, const float* __restrict__ b1,
                              const float* __restrict__ w2, const float* __restrict__ b2,
                              const float* __restrict__ w3, const float* __restrict__ b3,
                              float* __restrict__ fx) {
    int w = blockIdx.x * 4 + (threadIdx.x >> 6);
    int lane = threadIdx.x & 63;
    int b = w / NRR, r = w % NRR;
    // x_node = (sum_s dotpart[r][s][b]) / n + bbar[r]
    float s = (lane < SPLITS) ? dotpart[((size_t)(r*SPLITS + lane))*B_SZ + b] : 0.f;
    #pragma unroll
    for (int off = 32; off > 0; off >>= 1) s += __shfl_xor(s, off);
    float xn = s / (float)counts[r] + bbar[r];

    float h1 = fmaxf(xn * w1[r*64 + lane] + b1[r*64 + lane], 0.f);
    const float* w2row = w2 + ((size_t)r*64 + lane) * 64;
    float acc = b2[r*64 + lane];
    #pragma unroll
    for (int i = 0; i < 64; ++i) acc += __shfl(h1, i) * w2row[i];
    float h2 = fmaxf(acc, 0.f);
    float p = h2 * w3[r*64 + lane];
    for (int sft = 32; sft > 0; sft >>= 1) p += __shfl_down(p, sft);
    if (lane == 0) fx[b * NRR + r] = p + b3[r];
}

// ---------- distance MLP: one wave per pair p ----------
__global__ void dist_mlp_kernel(const float* __restrict__ dist,
                                const float* __restrict__ mw1, const float* __restrict__ mb1,
                                const float* __restrict__ mw2, const float* __restrict__ mb2,
                                const float* __restrict__ mw3, const float* __restrict__ mb3,
                                float* __restrict__ md) {
    int p = blockIdx.x * 4 + (threadIdx.x >> 6);
    int lane = threadIdx.x & 63;
    float d = dist[p];
    float g1 = fmaxf(d * mw1[lane] + mb1[lane], 0.f);
    const float* w2row = mw2 + lane * 64;
    float acc = mb2[lane];
    #pragma unroll
    for (int i = 0; i < 64; ++i) acc += __shfl(g1, i) * w2row[i];
    float g2 = fmaxf(acc, 0.f);
    float t = g2 * mw3[lane];
    for (int s = 32; s > 0; s >>= 1) t += __shfl_down(t, s);
    if (lane == 0) md[p] = t + mb3[0];
}

// ---------- fc1 partials: grid (64,4) -> mmatpart[j][q] ----------
__global__ __launch_bounds__(256) void fc1_kernel(const float* __restrict__ fc1_w,
                                                  const float* __restrict__ md,
                                                  float* __restrict__ mmatpart) {
    const int j = blockIdx.x, q = blockIdx.y;
    const int p0 = q * (NP/4), p1 = p0 + (NP/4);
    const float* row = fc1_w + (size_t)j * NP;
    float s = 0.f;
    for (int p = p0 + threadIdx.x; p < p1; p += 256) s += row[p] * md[p];
    __shared__ float red[4];
    for (int sft = 32; sft > 0; sft >>= 1) s += __shfl_down(s, sft);
    if ((threadIdx.x & 63) == 0) red[threadIdx.x >> 6] = s;
    __syncthreads();
    if (threadIdx.x == 0) mmatpart[j*4 + q] = red[0] + red[1] + red[2] + red[3];
}

// ---------- weff partials: grid (2,8) -> weffpart[jb][310] ----------
#define WPAD 310
__global__ __launch_bounds__(256) void weff_kernel(const float* __restrict__ hidden_w,
                                                   const float* __restrict__ hidden_b,
                                                   const float* __restrict__ out_w,
                                                   const float* __restrict__ out_b,
                                                   float* __restrict__ weffpart) {
    const int k = blockIdx.x * 256 + threadIdx.x;
    const int jb = blockIdx.y;
    const int j0 = jb * 96, j1 = j0 + 96;
    if (k < CATN) {
        float s = 0.f;
        for (int j = j0; j < j1; ++j) s += hidden_w[(size_t)j * CATN + k] * out_w[j];
        weffpart[jb*WPAD + k] = s;
    } else if (k == CATN) {
        float s = 0.f;
        for (int j = j0; j < j1; ++j) s += hidden_b[j] * out_w[j];
        weffpart[jb*WPAD + CATN] = s + (jb == 0 ? out_b[0] : 0.f);
    }
}

// ---------- fused tail: mmat combine + cat + out. 1 block, 512 threads ----------
__global__ __launch_bounds__(512) void tail_kernel(const float* __restrict__ mmatpart,
                                                   const float* __restrict__ fc1_b,
                                                   const float* __restrict__ fx,
                                                   const float* __restrict__ xbar,
                                                   const float* __restrict__ weffpart,
                                                   float* __restrict__ out) {
    __shared__ float mmat[64];
    __shared__ float cat[B_SZ][CATN];
    if (threadIdx.x < 64) {
        const float* p = mmatpart + threadIdx.x*4;
        mmat[threadIdx.x] = p[0] + p[1] + p[2] + p[3] + fc1_b[threadIdx.x];
    }
    __syncthreads();
    for (int idx = threadIdx.x; idx < B_SZ * NRR; idx += 512) {
        int b = idx / NRR, r = idx % NRR;
        float s = 0.f;
        #pragma unroll
        for (int kk = 0; kk < 8; ++kk) s += mmat[b*8 + kk] * fx[kk * NRR + r];
        cat[b][r] = s;
    }
    for (int idx = threadIdx.x; idx < B_SZ * 192; idx += 512) {
        int b = idx / 192, c = idx % 192;
        float s = 0.f;
        #pragma unroll
        for (int j = 0; j < 8; ++j) s += xbar[b * CIN + c*8 + j];
        cat[b][NRR + c] = s * (1.0f / 8.0f);
    }
    __syncthreads();
    const int b = threadIdx.x >> 6, lane = threadIdx.x & 63;
    float s = 0.f;
    for (int k = lane; k < CATN; k += 64) {
        float wk = 0.f;
        #pragma unroll
        for (int jb = 0; jb < 8; ++jb) wk += weffpart[jb*WPAD + k];
        s += cat[b][k] * wk;
    }
    for (int sft = 32; sft > 0; sft >>= 1) s += __shfl_down(s, sft);
    if (lane == 0) {
        float beff = 0.f;
        #pragma unroll
        for (int jb = 0; jb < 8; ++jb) beff += weffpart[jb*WPAD + CATN];
        out[b] = s + beff;
    }
}

extern "C" void kernel_launch(void* const* d_in, const int* in_sizes, int n_in,
                              void* d_out, int out_size, void* d_ws, size_t ws_size,
                              hipStream_t stream) {
    const float* x        = (const float*)d_in[0];
    const int*   labels   = (const int*)d_in[1];
    const float* dist     = (const float*)d_in[2];
    const float* fc_w     = (const float*)d_in[3];
    const float* fc_b     = (const float*)d_in[4];
    const float* fs_w1    = (const float*)d_in[5];
    const float* fs_b1    = (const float*)d_in[6];
    const float* fs_w2    = (const float*)d_in[7];
    const float* fs_b2    = (const float*)d_in[8];
    const float* fs_w3    = (const float*)d_in[9];
    const float* fs_b3    = (const float*)d_in[10];
    const float* m_w1     = (const float*)d_in[11];
    const float* m_b1     = (const float*)d_in[12];
    const float* m_w2     = (const float*)d_in[13];
    const float* m_b2     = (const float*)d_in[14];
    const float* m_w3     = (const float*)d_in[15];
    const float* m_b3     = (const float*)d_in[16];
    const float* fc1_w    = (const float*)d_in[17];
    const float* fc1_b    = (const float*)d_in[18];
    const float* hidden_w = (const float*)d_in[19];
    const float* hidden_b = (const float*)d_in[20];
    const float* out_w    = (const float*)d_in[21];
    const float* out_b    = (const float*)d_in[22];
    float* out = (float*)d_out;

    // workspace layout
    int* counts    = (int*)d_ws;               // 128
    int* offsets   = counts + 128;             // 128
    int* blockHist = offsets + 128;            // NRR*VB
    int* blockBase = blockHist + NRR*VB;       // NRR*VB
    int* perm      = blockBase + NRR*VB;       // V_TOT
    float* fb = (float*)(perm + ((V_TOT + 255) / 256) * 256);
    float* dotpart  = fb;  fb += (size_t)NRR * SPLITS * B_SZ;  // 40832
    float* bbar     = fb;  fb += 128;
    float* xbar     = fb;  fb += B_SZ * CIN;
    float* fx       = fb;  fb += B_SZ * NRR;
    float* md       = fb;  fb += NP;
    float* mmatpart = fb;  fb += 256;
    float* weffpart = fb;  fb += 8 * WPAD;

    hist_kernel<<<VB, 256, 0, stream>>>(labels, blockHist);
    binscan_kernel<<<NRR, 256, 0, stream>>>(blockHist, blockBase, counts);
    offsets_kernel<<<1, 64, 0, stream>>>(counts, offsets);
    xbar_kernel<<<(B_SZ * CIN + 255) / 256, 256, 0, stream>>>(x, xbar);
    scatter_kernel<<<VB, 256, 0, stream>>>(labels, offsets, blockBase, perm);
    roi_partial_dot_kernel<<<dim3(NRR, SPLITS), 384, 0, stream>>>(fc_w, perm, counts, offsets, xbar, dotpart);
    roi_reduce_b_kernel<<<NRR, 64, 0, stream>>>(fc_b, perm, counts, offsets, bbar);
    dist_mlp_kernel<<<NP / 4, 256, 0, stream>>>(dist, m_w1, m_b1, m_w2, m_b2, m_w3, m_b3, md);
    fc1_kernel<<<dim3(64, 4), 256, 0, stream>>>(fc1_w, md, mmatpart);
    weff_kernel<<<dim3(2, 8), 256, 0, stream>>>(hidden_w, hidden_b, out_w, out_b, weffpart);
    fs_mlp_kernel<<<232, 256, 0, stream>>>(dotpart, counts, bbar, fs_w1, fs_b1, fs_w2, fs_b2, fs_w3, fs_b3, fx);
    tail_kernel<<<1, 512, 0, stream>>>(mmatpart, fc1_b, fx, xbar, weffpart, out);
}